// Round 9
// baseline (115.878 us; speedup 1.0000x reference)
//
#include <hip/hip_runtime.h>
#include <hip/hip_bf16.h>
#include <math.h>

#define HD 256
#define BB 64
#define DD 2048
#define NCHK 8          // 256-row chunks per batch
#define NT 8            // 32-row tiles per chunk

typedef __attribute__((ext_vector_type(8))) short  short8;
typedef __attribute__((ext_vector_type(4))) float  float4v;
typedef __attribute__((ext_vector_type(4))) unsigned uint4v;
typedef __attribute__((ext_vector_type(4))) unsigned short ushort4v;

__device__ inline unsigned short f2bf(float f) {
    unsigned u = __builtin_bit_cast(unsigned, f);
    u += 0x7FFFu + ((u >> 16) & 1u);   // RNE
    return (unsigned short)(u >> 16);
}

__device__ inline unsigned cvt_pk_bf16(float lo, float hi) {
    unsigned r;
    asm("v_cvt_pk_bf16_f32 %0, %1, %2" : "=v"(r) : "v"(lo), "v"(hi));
    return r;
}
__device__ inline short8 cvt8(float4v lo, float4v hi) {
    uint4v u;
    u[0] = cvt_pk_bf16(lo[0], lo[1]);
    u[1] = cvt_pk_bf16(lo[2], lo[3]);
    u[2] = cvt_pk_bf16(hi[0], hi[1]);
    u[3] = cvt_pk_bf16(hi[2], hi[3]);
    return __builtin_bit_cast(short8, u);
}

__device__ inline float fast_exp2(float x) {
    float r;
    asm("v_exp_f32 %0, %1" : "=v"(r) : "v"(x));
    return r;
}
__device__ inline float fast_expf(float x) { return fast_exp2(x * 1.4426950408889634f); }
__device__ inline float fast_tanh(float x) {
    float y = x * 2.8853900817779268f;          // 2x * log2(e)
    y = fminf(fmaxf(y, -30.f), 30.f);
    float t = fast_exp2(y);
    float r;
    asm("v_rcp_f32 %0, %1" : "=v"(r) : "v"(t + 1.f));
    return (t - 1.f) * r;
}

// LDS-only barrier: orders LDS traffic without draining vmcnt -> reg prefetch
// loads stay in flight across it.
#define SYNC_LDS() do { asm volatile("s_waitcnt lgkmcnt(0)" ::: "memory"); \
                        __builtin_amdgcn_s_barrier(); \
                        asm volatile("" ::: "memory"); } while (0)

// ---------------- kernel 0 (fused prep): W1 f32->bf16  AND  g23 ----------------
__global__ __launch_bounds__(256) void k_prep(const float* __restrict__ W1,
                                              unsigned short* __restrict__ w1b,
                                              const float* __restrict__ ctx,
                                              const float* __restrict__ hid,
                                              const float* __restrict__ W2,
                                              const float* __restrict__ b2,
                                              const float* __restrict__ W3,
                                              float* __restrict__ g23) {
    if (blockIdx.x < 64) {
        int i = blockIdx.x * 256 + threadIdx.x;
        float4v v = ((const float4v*)W1)[i];
        ushort4v o;
        o[0] = f2bf(v[0]); o[1] = f2bf(v[1]); o[2] = f2bf(v[2]); o[3] = f2bf(v[3]);
        ((ushort4v*)w1b)[i] = o;
    } else {
        int b = blockIdx.x - 64, t = threadIdx.x;
        __shared__ float c[HD], hh[HD];
        c[t]  = ctx[b * HD + t];
        hh[t] = hid[b * HD + t];
        __syncthreads();
        const float4v* w2 = (const float4v*)(W2 + (size_t)t * HD);
        const float4v* w3 = (const float4v*)(W3 + (size_t)t * HD);
        float acc = b2[t];
        #pragma unroll 8
        for (int k = 0; k < 64; ++k) {
            float4v a = w2[k], d = w3[k];
            int k4 = k * 4;
            acc += c[k4] * a[0] + c[k4 + 1] * a[1] + c[k4 + 2] * a[2] + c[k4 + 3] * a[3];
            acc += hh[k4] * d[0] + hh[k4 + 1] * d[1] + hh[k4 + 2] * d[2] + hh[k4 + 3] * d[3];
        }
        g23[b * HD + t] = acc;
    }
}

// ---------------- kernel 1: scores[b,d] = W4 . tanh(q@W1^T + g23) --------------
// grid (8, 64), 512 thr (8 waves, wave owns 32 h, bfr = 64 VGPR). Block does
// 8x 32-row tiles; bf16 dbuf LDS (2x16KB, XOR-swizzled); reg-staged with
// cvt_pk; 2 LDS-only barriers/tile; next tile's loads fly across the whole
// passA. __launch_bounds__(512,4): ~120 VGPR budget -> 2 blocks/CU (16 waves).
__global__ __launch_bounds__(512, 4) void k_scores(const float* __restrict__ q,
                                                   const unsigned short* __restrict__ w1b,
                                                   const float* __restrict__ g23,
                                                   const float* __restrict__ W4,
                                                   float* __restrict__ scores) {
    __shared__ __attribute__((aligned(16))) unsigned short tile[2][32 * HD]; // 2 x 16 KB
    __shared__ float sp[8][32];

    const int t = threadIdx.x;
    const int chunk = blockIdx.x, b = blockIdx.y;
    const int lane = t & 63, wave = t >> 6;
    const int l15 = lane & 15, lk = lane >> 4;
    const int hb = wave * 32;

    const float* qc = q + ((size_t)b * DD + chunk * 256) * HD;

    // staging geometry: thread covers row sr (32 rows x 16 thr), 16 f32 at col sc
    const int sr = t >> 4, sc = (t & 15) * 16;

    // prologue: issue tile-0 loads (4 x dwordx4, 16 VGPR)
    float4v st0, st1, st2, st3;
    {
        const float4v* src = (const float4v*)(qc + (size_t)sr * HD + sc);
        st0 = src[0]; st1 = src[1]; st2 = src[2]; st3 = src[3];
    }

    // W1 slice (A operand) -> 64 VGPR (L2-hot after k_prep)
    short8 bfr[8][2];
    #pragma unroll
    for (int kb = 0; kb < 8; ++kb)
        #pragma unroll
        for (int nf = 0; nf < 2; ++nf)
            bfr[kb][nf] = *(const short8*)&w1b[(size_t)(hb + nf * 16 + l15) * HD + kb * 32 + lk * 8];

    // per-lane g23/W4 for C rows h = hb + nf*16 + lk*4 + r
    float gv[2][4], wv[2][4];
    #pragma unroll
    for (int nf = 0; nf < 2; ++nf)
        #pragma unroll
        for (int r = 0; r < 4; ++r) {
            int h = hb + nf * 16 + lk * 4 + r;
            gv[nf][r] = g23[b * HD + h];
            wv[nf][r] = W4[h];
        }

    int cur = 0;
    #pragma unroll 1
    for (int st = 0; st < NT; ++st) {
        // convert prefetched regs -> swizzled bf16 store (compiler waits vmcnt here)
        {
            short8 p0 = cvt8(st0, st1);
            short8 p1 = cvt8(st2, st3);
            int base = sr * 512 + (t & 15) * 32;
            int sw = (sr & 7) << 4;
            *(short8*)((char*)tile[cur] + ((base) ^ sw))      = p0;
            *(short8*)((char*)tile[cur] + ((base + 16) ^ sw)) = p1;
        }
        // issue next tile's loads: fly across both barriers + passA
        if (st + 1 < NT) {
            const float4v* src = (const float4v*)(qc + (size_t)((st + 1) * 32 + sr) * HD + sc);
            st0 = src[0]; st1 = src[1]; st2 = src[2]; st3 = src[3];
        }
        SYNC_LDS();                      // (A) tile[cur] staged by all waves

        // passA: C[h][d] = sum_k W1[h][k] q[d][k], d in 2 blocks of 16
        #pragma unroll
        for (int mf = 0; mf < 2; ++mf) {
            float4v a0 = {0.f, 0.f, 0.f, 0.f}, a1 = {0.f, 0.f, 0.f, 0.f};
            const int d = mf * 16 + l15;
            const int dsw = (d & 7) << 4;
            #pragma unroll
            for (int kb = 0; kb < 8; ++kb) {
                int byte = d * 512 + kb * 64 + lk * 16;
                short8 bq = *(const short8*)((const char*)tile[cur] + (byte ^ dsw));
                a0 = __builtin_amdgcn_mfma_f32_16x16x32_bf16(bfr[kb][0], bq, a0, 0, 0, 0);
                a1 = __builtin_amdgcn_mfma_f32_16x16x32_bf16(bfr[kb][1], bq, a1, 0, 0, 0);
            }
            float s = 0.f;
            #pragma unroll
            for (int r = 0; r < 4; ++r) s += fast_tanh(a0[r] + gv[0][r]) * wv[0][r];
            #pragma unroll
            for (int r = 0; r < 4; ++r) s += fast_tanh(a1[r] + gv[1][r]) * wv[1][r];
            s += __shfl_xor(s, 16, 64);
            s += __shfl_xor(s, 32, 64);
            if (lk == 0) sp[wave][mf * 16 + l15] = s;
        }
        SYNC_LDS();                      // (B) sp published

        if (t < 32) {
            float s = sp[0][t] + sp[1][t] + sp[2][t] + sp[3][t]
                    + sp[4][t] + sp[5][t] + sp[6][t] + sp[7][t];
            scores[b * DD + chunk * 256 + st * 32 + t] = s;  // b4 dropped (shift-inv)
        }
        cur ^= 1;
    }
}

// ---------------- kernel 2: per-batch softmax stats ----------------
__global__ __launch_bounds__(256) void k_stats(const float* __restrict__ scores,
                                               float* __restrict__ stats) {
    int b = blockIdx.x, t = threadIdx.x;
    __shared__ float red[256];
    float sv[8];
    float lm = -1e30f;
    #pragma unroll
    for (int i = 0; i < 8; ++i) {
        sv[i] = scores[b * DD + t + i * 256];
        lm = fmaxf(lm, sv[i]);
    }
    red[t] = lm; __syncthreads();
    for (int s = 128; s > 0; s >>= 1) {
        if (t < s) red[t] = fmaxf(red[t], red[t + s]);
        __syncthreads();
    }
    float mx = red[0];
    __syncthreads();
    float ls = 0.f;
    #pragma unroll
    for (int i = 0; i < 8; ++i) ls += fast_expf(sv[i] - mx);
    red[t] = ls; __syncthreads();
    for (int s = 128; s > 0; s >>= 1) {
        if (t < s) red[t] += red[t + s];
        __syncthreads();
    }
    if (t == 0) { stats[b * 2] = mx; stats[b * 2 + 1] = 1.f / red[0]; }
}

// ---------------- kernel 3: partial weighted sums (L3-hot second q pass) -------
__global__ __launch_bounds__(256) void k_pout(const float* __restrict__ q,
                                              const float* __restrict__ scores,
                                              const float* __restrict__ stats,
                                              float* __restrict__ part) {
    const int b = blockIdx.y, ch = blockIdx.x, t = threadIdx.x;
    __shared__ float wl[256];
    __shared__ float4v red[256];
    const float mx = stats[b * 2], inv = stats[b * 2 + 1];
    const int d0 = ch * 256;
    wl[t] = fast_expf(scores[b * DD + d0 + t] - mx) * inv;
    __syncthreads();
    const int rg = t >> 6, cg = t & 63;       // row-group, col-float4
    const float4v* qb = (const float4v*)(q + ((size_t)(b * DD + d0 + rg)) * HD) + cg;
    float4v a0 = {0,0,0,0}, a1 = {0,0,0,0};
    #pragma unroll 8
    for (int i = 0; i < 64; i += 2) {
        a0 += qb[(size_t)i * 256]       * wl[rg + i * 4];
        a1 += qb[(size_t)(i + 1) * 256] * wl[rg + (i + 1) * 4];
    }
    red[t] = a0 + a1;
    __syncthreads();
    if (t < 64) {
        float4v s = red[t] + red[t + 64] + red[t + 128] + red[t + 192];
        ((float4v*)part)[((size_t)(b * 8 + ch)) * 64 + t] = s;
    }
}

// ---------------- kernel 4: reduce partials ----------------
__global__ __launch_bounds__(64) void k_rout(const float* __restrict__ part,
                                             float* __restrict__ out) {
    int b = blockIdx.x, t = threadIdx.x;
    float4v s = {0,0,0,0};
    #pragma unroll
    for (int c = 0; c < 8; ++c) s += ((const float4v*)part)[((size_t)(b * 8 + c)) * 64 + t];
    ((float4v*)out)[b * 64 + t] = s;
}

extern "C" void kernel_launch(void* const* d_in, const int* in_sizes, int n_in,
                              void* d_out, int out_size, void* d_ws, size_t ws_size,
                              hipStream_t stream) {
    (void)in_sizes; (void)n_in; (void)out_size; (void)ws_size;
    const float* ctx = (const float*)d_in[0];
    const float* q   = (const float*)d_in[1];
    const float* hid = (const float*)d_in[2];
    const float* W1  = (const float*)d_in[3];
    const float* W2  = (const float*)d_in[4];
    const float* b2  = (const float*)d_in[5];
    const float* W3  = (const float*)d_in[6];
    const float* W4  = (const float*)d_in[7];
    // d_in[8] = b4: dropped (softmax shift-invariant)
    float* out = (float*)d_out;

    char* ws = (char*)d_ws;
    unsigned short* w1b = (unsigned short*)(ws);            // 131072 B
    float* g23    = (float*)(ws + 131072);                  //  65536 B
    float* scores = (float*)(ws + 196608);                  // 524288 B
    float* stats  = (float*)(ws + 720896);                  //    512 B
    float* part   = (float*)(ws + 721408);                  // 524288 B

    k_prep  <<<dim3(128), dim3(256), 0, stream>>>(W1, w1b, ctx, hid, W2, b2, W3, g23);
    k_scores<<<dim3(NCHK, BB), dim3(512), 0, stream>>>(q, w1b, g23, W4, scores);
    k_stats <<<dim3(BB), dim3(256), 0, stream>>>(scores, stats);
    k_pout  <<<dim3(8, BB), dim3(256), 0, stream>>>(q, scores, stats, part);
    k_rout  <<<dim3(BB), dim3(64), 0, stream>>>(part, out);
}

// Round 10
// 79.161 us; speedup vs baseline: 1.4638x; 1.4638x over previous
//
#include <hip/hip_runtime.h>
#include <hip/hip_bf16.h>
#include <math.h>

#define HD 256
#define BB 64
#define DD 2048
#define NCHK 8          // 256-row chunks per batch
#define NT 8            // 32-row tiles per chunk

typedef __attribute__((ext_vector_type(8))) short  short8;
typedef __attribute__((ext_vector_type(4))) float  float4v;
typedef __attribute__((ext_vector_type(4))) unsigned uint4v;
typedef __attribute__((ext_vector_type(4))) unsigned short ushort4v;

__device__ inline unsigned short f2bf(float f) {
    unsigned u = __builtin_bit_cast(unsigned, f);
    u += 0x7FFFu + ((u >> 16) & 1u);   // RNE
    return (unsigned short)(u >> 16);
}

__device__ inline unsigned cvt_pk_bf16(float lo, float hi) {
    unsigned r;
    asm("v_cvt_pk_bf16_f32 %0, %1, %2" : "=v"(r) : "v"(lo), "v"(hi));
    return r;
}
__device__ inline short8 cvt8(float4v lo, float4v hi) {
    uint4v u;
    u[0] = cvt_pk_bf16(lo[0], lo[1]);
    u[1] = cvt_pk_bf16(lo[2], lo[3]);
    u[2] = cvt_pk_bf16(hi[0], hi[1]);
    u[3] = cvt_pk_bf16(hi[2], hi[3]);
    return __builtin_bit_cast(short8, u);
}

__device__ inline float fast_exp2(float x) {
    float r;
    asm("v_exp_f32 %0, %1" : "=v"(r) : "v"(x));
    return r;
}
__device__ inline float fast_expf(float x) { return fast_exp2(x * 1.4426950408889634f); }
__device__ inline float fast_tanh(float x) {
    float y = x * 2.8853900817779268f;          // 2x * log2(e)
    y = fminf(fmaxf(y, -30.f), 30.f);
    float t = fast_exp2(y);
    float r;
    asm("v_rcp_f32 %0, %1" : "=v"(r) : "v"(t + 1.f));
    return (t - 1.f) * r;
}

// LDS-only barrier: orders LDS traffic without draining vmcnt -> prefetch
// global loads stay in flight across it.
#define SYNC_LDS() do { asm volatile("s_waitcnt lgkmcnt(0)" ::: "memory"); \
                        __builtin_amdgcn_s_barrier(); \
                        asm volatile("" ::: "memory"); } while (0)

// ---------------- kernel 0 (fused prep): W1 f32->bf16  AND  g23 ----------------
__global__ __launch_bounds__(256) void k_prep(const float* __restrict__ W1,
                                              unsigned short* __restrict__ w1b,
                                              const float* __restrict__ ctx,
                                              const float* __restrict__ hid,
                                              const float* __restrict__ W2,
                                              const float* __restrict__ b2,
                                              const float* __restrict__ W3,
                                              float* __restrict__ g23) {
    if (blockIdx.x < 64) {
        int i = blockIdx.x * 256 + threadIdx.x;
        float4v v = ((const float4v*)W1)[i];
        ushort4v o;
        o[0] = f2bf(v[0]); o[1] = f2bf(v[1]); o[2] = f2bf(v[2]); o[3] = f2bf(v[3]);
        ((ushort4v*)w1b)[i] = o;
    } else {
        int b = blockIdx.x - 64, t = threadIdx.x;
        __shared__ float c[HD], hh[HD];
        c[t]  = ctx[b * HD + t];
        hh[t] = hid[b * HD + t];
        __syncthreads();
        const float4v* w2 = (const float4v*)(W2 + (size_t)t * HD);
        const float4v* w3 = (const float4v*)(W3 + (size_t)t * HD);
        float acc = b2[t];
        #pragma unroll 8
        for (int k = 0; k < 64; ++k) {
            float4v a = w2[k], d = w3[k];
            int k4 = k * 4;
            acc += c[k4] * a[0] + c[k4 + 1] * a[1] + c[k4 + 2] * a[2] + c[k4 + 3] * a[3];
            acc += hh[k4] * d[0] + hh[k4 + 1] * d[1] + hh[k4 + 2] * d[2] + hh[k4 + 3] * d[3];
        }
        g23[b * HD + t] = acc;
    }
}

// ---------------- kernel 1: scores[b,d] = W4 . tanh(q@W1^T + g23) --------------
// grid (8, 64), 512 thr (8 waves; wave owns 32 h, bfr = 64 VGPR).
// Per 32-row tile: ONE barrier. Wave accumulates its h-partial into a
// privately-owned sp_acc row (no cross-wave sync); 8-way h-sum once at end.
// Occupancy via small LDS (41 KB); NO min-blocks clause (r7/r9 spill lessons).
__global__ __launch_bounds__(512) void k_scores(const float* __restrict__ q,
                                                const unsigned short* __restrict__ w1b,
                                                const float* __restrict__ g23,
                                                const float* __restrict__ W4,
                                                float* __restrict__ scores) {
    __shared__ __attribute__((aligned(16))) unsigned short tile[2][32 * HD]; // 2 x 16 KB
    __shared__ float sp_acc[8][HD];                                          // 8 KB

    const int t = threadIdx.x;
    const int chunk = blockIdx.x, b = blockIdx.y;
    const int lane = t & 63, wave = t >> 6;
    const int l15 = lane & 15, lk = lane >> 4;
    const int hb = wave * 32;

    const float* qc = q + ((size_t)b * DD + chunk * 256) * HD;

    // staging geometry: thread covers row sr (32 rows x 16 thr), 16 f32 at col sc
    const int sr = t >> 4, sc = (t & 15) * 16;

    // prologue: issue tile-0 loads (4 x dwordx4, 16 VGPR)
    float4v st0, st1, st2, st3;
    {
        const float4v* src = (const float4v*)(qc + (size_t)sr * HD + sc);
        st0 = src[0]; st1 = src[1]; st2 = src[2]; st3 = src[3];
    }

    // W1 slice (A operand) -> 64 VGPR (L2-hot after k_prep)
    short8 bfr[8][2];
    #pragma unroll
    for (int kb = 0; kb < 8; ++kb)
        #pragma unroll
        for (int nf = 0; nf < 2; ++nf)
            bfr[kb][nf] = *(const short8*)&w1b[(size_t)(hb + nf * 16 + l15) * HD + kb * 32 + lk * 8];

    // per-lane g23/W4 for C rows h = hb + nf*16 + lk*4 + r
    float gv[2][4], wv[2][4];
    #pragma unroll
    for (int nf = 0; nf < 2; ++nf)
        #pragma unroll
        for (int r = 0; r < 4; ++r) {
            int h = hb + nf * 16 + lk * 4 + r;
            gv[nf][r] = g23[b * HD + h];
            wv[nf][r] = W4[h];
        }

    int cur = 0;
    #pragma unroll 1
    for (int st = 0; st < NT; ++st) {
        // convert prefetched regs -> swizzled bf16 store (compiler waits vmcnt here)
        {
            short8 p0 = cvt8(st0, st1);
            short8 p1 = cvt8(st2, st3);
            int base = sr * 512 + (t & 15) * 32;
            int sw = (sr & 7) << 4;
            *(short8*)((char*)tile[cur] + ((base) ^ sw))      = p0;
            *(short8*)((char*)tile[cur] + ((base + 16) ^ sw)) = p1;
        }
        // issue next tile's loads: fly across the barrier + whole passA
        if (st + 1 < NT) {
            const float4v* src = (const float4v*)(qc + (size_t)((st + 1) * 32 + sr) * HD + sc);
            st0 = src[0]; st1 = src[1]; st2 = src[2]; st3 = src[3];
        }
        SYNC_LDS();   // tile[cur] staged by all waves; prev-tile reads all drained

        // passA: C[h][d] = sum_k W1[h][k] q[d][k], d in 2 blocks of 16
        float s0, s1;
        {
            float4v a0 = {0.f, 0.f, 0.f, 0.f}, a1 = {0.f, 0.f, 0.f, 0.f};
            const int d = l15;
            const int dsw = (d & 7) << 4;
            #pragma unroll
            for (int kb = 0; kb < 8; ++kb) {
                int byte = d * 512 + kb * 64 + lk * 16;
                short8 bq = *(const short8*)((const char*)tile[cur] + (byte ^ dsw));
                a0 = __builtin_amdgcn_mfma_f32_16x16x32_bf16(bfr[kb][0], bq, a0, 0, 0, 0);
                a1 = __builtin_amdgcn_mfma_f32_16x16x32_bf16(bfr[kb][1], bq, a1, 0, 0, 0);
            }
            float s = 0.f;
            #pragma unroll
            for (int r = 0; r < 4; ++r) s += fast_tanh(a0[r] + gv[0][r]) * wv[0][r];
            #pragma unroll
            for (int r = 0; r < 4; ++r) s += fast_tanh(a1[r] + gv[1][r]) * wv[1][r];
            s += __shfl_xor(s, 16, 64);
            s += __shfl_xor(s, 32, 64);
            s0 = s;
        }
        {
            float4v a0 = {0.f, 0.f, 0.f, 0.f}, a1 = {0.f, 0.f, 0.f, 0.f};
            const int d = 16 + l15;
            const int dsw = (d & 7) << 4;
            #pragma unroll
            for (int kb = 0; kb < 8; ++kb) {
                int byte = d * 512 + kb * 64 + lk * 16;
                short8 bq = *(const short8*)((const char*)tile[cur] + (byte ^ dsw));
                a0 = __builtin_amdgcn_mfma_f32_16x16x32_bf16(bfr[kb][0], bq, a0, 0, 0, 0);
                a1 = __builtin_amdgcn_mfma_f32_16x16x32_bf16(bfr[kb][1], bq, a1, 0, 0, 0);
            }
            float s = 0.f;
            #pragma unroll
            for (int r = 0; r < 4; ++r) s += fast_tanh(a0[r] + gv[0][r]) * wv[0][r];
            #pragma unroll
            for (int r = 0; r < 4; ++r) s += fast_tanh(a1[r] + gv[1][r]) * wv[1][r];
            s += __shfl_xor(s, 16, 64);
            s += __shfl_xor(s, 32, 64);
            s1 = s;
        }
        // wave-private accumulator row: no cross-wave sync needed
        float sv = (lane < 16) ? s0 : s1;
        if (lane < 32) sp_acc[wave][st * 32 + lane] = sv;

        cur ^= 1;
    }

    // end-of-kernel: single cross-wave sum over the 8 wave rows
    SYNC_LDS();
    if (t < HD) {
        float s = sp_acc[0][t] + sp_acc[1][t] + sp_acc[2][t] + sp_acc[3][t]
                + sp_acc[4][t] + sp_acc[5][t] + sp_acc[6][t] + sp_acc[7][t];
        scores[b * DD + chunk * 256 + t] = s;   // b4 dropped (softmax shift-inv)
    }
}

// ---------------- kernel 2: per-batch softmax stats ----------------
__global__ __launch_bounds__(256) void k_stats(const float* __restrict__ scores,
                                               float* __restrict__ stats) {
    int b = blockIdx.x, t = threadIdx.x;
    __shared__ float red[256];
    float sv[8];
    float lm = -1e30f;
    #pragma unroll
    for (int i = 0; i < 8; ++i) {
        sv[i] = scores[b * DD + t + i * 256];
        lm = fmaxf(lm, sv[i]);
    }
    red[t] = lm; __syncthreads();
    for (int s = 128; s > 0; s >>= 1) {
        if (t < s) red[t] = fmaxf(red[t], red[t + s]);
        __syncthreads();
    }
    float mx = red[0];
    __syncthreads();
    float ls = 0.f;
    #pragma unroll
    for (int i = 0; i < 8; ++i) ls += fast_expf(sv[i] - mx);
    red[t] = ls; __syncthreads();
    for (int s = 128; s > 0; s >>= 1) {
        if (t < s) red[t] += red[t + s];
        __syncthreads();
    }
    if (t == 0) { stats[b * 2] = mx; stats[b * 2 + 1] = 1.f / red[0]; }
}

// ---------------- kernel 3: partial weighted sums (L3-hot second q pass) -------
__global__ __launch_bounds__(256) void k_pout(const float* __restrict__ q,
                                              const float* __restrict__ scores,
                                              const float* __restrict__ stats,
                                              float* __restrict__ part) {
    const int b = blockIdx.y, ch = blockIdx.x, t = threadIdx.x;
    __shared__ float wl[256];
    __shared__ float4v red[256];
    const float mx = stats[b * 2], inv = stats[b * 2 + 1];
    const int d0 = ch * 256;
    wl[t] = fast_expf(scores[b * DD + d0 + t] - mx) * inv;
    __syncthreads();
    const int rg = t >> 6, cg = t & 63;       // row-group, col-float4
    const float4v* qb = (const float4v*)(q + ((size_t)(b * DD + d0 + rg)) * HD) + cg;
    float4v a0 = {0,0,0,0}, a1 = {0,0,0,0};
    #pragma unroll 8
    for (int i = 0; i < 64; i += 2) {
        a0 += qb[(size_t)i * 256]       * wl[rg + i * 4];
        a1 += qb[(size_t)(i + 1) * 256] * wl[rg + (i + 1) * 4];
    }
    red[t] = a0 + a1;
    __syncthreads();
    if (t < 64) {
        float4v s = red[t] + red[t + 64] + red[t + 128] + red[t + 192];
        ((float4v*)part)[((size_t)(b * 8 + ch)) * 64 + t] = s;
    }
}

// ---------------- kernel 4: reduce partials ----------------
__global__ __launch_bounds__(64) void k_rout(const float* __restrict__ part,
                                             float* __restrict__ out) {
    int b = blockIdx.x, t = threadIdx.x;
    float4v s = {0,0,0,0};
    #pragma unroll
    for (int c = 0; c < 8; ++c) s += ((const float4v*)part)[((size_t)(b * 8 + c)) * 64 + t];
    ((float4v*)out)[b * 64 + t] = s;
}

extern "C" void kernel_launch(void* const* d_in, const int* in_sizes, int n_in,
                              void* d_out, int out_size, void* d_ws, size_t ws_size,
                              hipStream_t stream) {
    (void)in_sizes; (void)n_in; (void)out_size; (void)ws_size;
    const float* ctx = (const float*)d_in[0];
    const float* q   = (const float*)d_in[1];
    const float* hid = (const float*)d_in[2];
    const float* W1  = (const float*)d_in[3];
    const float* W2  = (const float*)d_in[4];
    const float* b2  = (const float*)d_in[5];
    const float* W3  = (const float*)d_in[6];
    const float* W4  = (const float*)d_in[7];
    // d_in[8] = b4: dropped (softmax shift-invariant)
    float* out = (float*)d_out;

    char* ws = (char*)d_ws;
    unsigned short* w1b = (unsigned short*)(ws);            // 131072 B
    float* g23    = (float*)(ws + 131072);                  //  65536 B
    float* scores = (float*)(ws + 196608);                  // 524288 B
    float* stats  = (float*)(ws + 720896);                  //    512 B
    float* part   = (float*)(ws + 721408);                  // 524288 B

    k_prep  <<<dim3(128), dim3(256), 0, stream>>>(W1, w1b, ctx, hid, W2, b2, W3, g23);
    k_scores<<<dim3(NCHK, BB), dim3(512), 0, stream>>>(q, w1b, g23, W4, scores);
    k_stats <<<dim3(BB), dim3(256), 0, stream>>>(scores, stats);
    k_pout  <<<dim3(8, BB), dim3(256), 0, stream>>>(q, scores, stats, part);
    k_rout  <<<dim3(BB), dim3(64), 0, stream>>>(part, out);
}